// Round 10
// baseline (342.298 us; speedup 1.0000x reference)
//
#include <hip/hip_runtime.h>

// Problem constants (fixed by setup_inputs): N=2048, D=512, H=8, dh=64, max_iter=5.
// Identity: exp(s/t + log(kern*yw+eps)) = exp(s/t) * (kern*yw+eps).
// E[h][n][m] = mask ? bf16(exp(s/(8t))) : 0 is loop-invariant (64 MB).
// ms_iter#5 stores g (bf16, 8 MB) + invz (fp32); av fuses A = bf16(E)*bf16(g)
// in registers; invz is a row scale applied in av_red.

typedef __attribute__((ext_vector_type(8))) short bf16x8;
typedef __attribute__((ext_vector_type(4))) float f32x4;

__device__ __forceinline__ unsigned short f2bf(float f) {
    unsigned int u = __float_as_uint(f);
    u += 0x7fff + ((u >> 16) & 1);   // RNE (inputs finite)
    return (unsigned short)(u >> 16);
}
__device__ __forceinline__ float bf2f(unsigned short u) {
    return __uint_as_float((unsigned int)u << 16);
}

union EU { bf16x8 v; unsigned short u[8]; };

// ---------------------------------------------------------------------------
// Convert strf + Wq/Wk/Wv/Wo fp32->bf16 (sW = [4][262144]) and dmask->byte.
// 8 elems/thread; grid 3072x256 exact.
// ---------------------------------------------------------------------------
__global__ __launch_bounds__(256)
void conv_all(const float* __restrict__ strf,
              const float* __restrict__ Wq, const float* __restrict__ Wk,
              const float* __restrict__ Wv, const float* __restrict__ Wo,
              const int* __restrict__ dmask,
              unsigned short* __restrict__ sA, unsigned short* __restrict__ sW,
              unsigned char* __restrict__ mby)
{
    const long base = (long)(blockIdx.x * 256 + threadIdx.x) * 8;
    if (base >= 2097152) {
        const long rel = base - 2097152;
        int4 a = *reinterpret_cast<const int4*>(dmask + rel);
        int4 b = *reinterpret_cast<const int4*>(dmask + rel + 4);
        unsigned long long p = 0;
        p |= (a.x > 0) ? 0x01ULL : 0;  p |= (a.y > 0) ? 0x0100ULL : 0;
        p |= (a.z > 0) ? 0x010000ULL : 0;  p |= (a.w > 0) ? 0x01000000ULL : 0;
        p |= (b.x > 0) ? 0x0100000000ULL : 0;  p |= (b.y > 0) ? 0x010000000000ULL : 0;
        p |= (b.z > 0) ? 0x01000000000000ULL : 0;  p |= (b.w > 0) ? 0x0100000000000000ULL : 0;
        *reinterpret_cast<unsigned long long*>(mby + rel) = p;
        return;
    }
    const float* src;
    unsigned short* dst;
    if (base < 1048576) {
        src = strf + base; dst = sA + base;
    } else {
        const long rel = base - 1048576;
        const int seg = (int)(rel >> 18);
        const long off = rel & 262143;
        const float* Ws[4] = {Wq, Wk, Wv, Wo};
        src = Ws[seg] + off;
        dst = sW + (long)seg * 262144 + off;
    }
    float4 a = *reinterpret_cast<const float4*>(src);
    float4 b = *reinterpret_cast<const float4*>(src + 4);
    EU o;
    o.u[0] = f2bf(a.x); o.u[1] = f2bf(a.y); o.u[2] = f2bf(a.z); o.u[3] = f2bf(a.w);
    o.u[4] = f2bf(b.x); o.u[5] = f2bf(b.y); o.u[6] = f2bf(b.z); o.u[7] = f2bf(b.w);
    *reinterpret_cast<bf16x8*>(dst) = o.v;
}

// ---------------------------------------------------------------------------
// q/k/v projection via bf16 MFMA. grid (32 n-tiles, 8 d-tiles, 3).
// z=0 -> qh, z=1 -> kh, z=2 -> vT (transposed direct store).
// ---------------------------------------------------------------------------
__global__ __launch_bounds__(256)
void qkv_mfma(const unsigned short* __restrict__ sA,
              const unsigned short* __restrict__ sW,
              const float* __restrict__ bq, const float* __restrict__ bk,
              const float* __restrict__ bv,
              unsigned short* __restrict__ qh, unsigned short* __restrict__ kh,
              unsigned short* __restrict__ vT)
{
    const int z  = blockIdx.z;
    const int bx = blockIdx.x;
    const int by = blockIdx.y;
    const int tid = threadIdx.x;
    const int wv = tid >> 6;
    const int lane = tid & 63;
    const int row  = lane & 15;
    const int koct = (lane >> 4) * 8;
    const int n0 = bx * 64;

    const unsigned short* Ap = sA + (long)(n0 + wv * 16 + row) * 512;
    const unsigned short* Bp = sW + (long)z * 262144 + (long)(by * 64 + row) * 512;

    f32x4 acc[4] = {};
#pragma unroll
    for (int k0 = 0; k0 < 512; k0 += 32) {
        bf16x8 a = *reinterpret_cast<const bf16x8*>(Ap + k0 + koct);
#pragma unroll
        for (int t = 0; t < 4; t++) {
            bf16x8 b = *reinterpret_cast<const bf16x8*>(Bp + (long)(t * 16) * 512 + k0 + koct);
            acc[t] = __builtin_amdgcn_mfma_f32_16x16x32_bf16(a, b, acc[t], 0, 0, 0);
        }
    }

    if (z == 2) {
        const int rbase = n0 + wv * 16 + (lane >> 4) * 4;
#pragma unroll
        for (int t = 0; t < 4; t++) {
            const int d = by * 64 + t * 16 + (lane & 15);
            const float bb = bv[d];
            ushort4 o;
            o.x = f2bf(acc[t][0] + bb); o.y = f2bf(acc[t][1] + bb);
            o.z = f2bf(acc[t][2] + bb); o.w = f2bf(acc[t][3] + bb);
            *reinterpret_cast<ushort4*>(vT + (long)d * 2048 + rbase) = o;
        }
        return;
    }

    __shared__ float ls[64][68];
    const int lrb = wv * 16 + (lane >> 4) * 4;
    const int lcb = lane & 15;
#pragma unroll
    for (int t = 0; t < 4; t++)
#pragma unroll
        for (int r = 0; r < 4; r++)
            ls[lrb + r][t * 16 + lcb] = acc[t][r];
    __syncthreads();

    const float* bias = (z == 0) ? bq : bk;
    unsigned short* dst = (z == 0) ? qh : kh;
    const int r2 = tid >> 2;
    const int c2 = (tid & 3) * 16;
    float sv[16];
#pragma unroll
    for (int j = 0; j < 4; j++) {
        float4 s = *reinterpret_cast<const float4*>(&ls[r2][c2 + j * 4]);
        float4 bb = *reinterpret_cast<const float4*>(bias + by * 64 + c2 + j * 4);
        sv[j*4+0] = s.x + bb.x; sv[j*4+1] = s.y + bb.y;
        sv[j*4+2] = s.z + bb.z; sv[j*4+3] = s.w + bb.w;
    }
    EU o0, o1;
#pragma unroll
    for (int j = 0; j < 8; j++) { o0.u[j] = f2bf(sv[j]); o1.u[j] = f2bf(sv[8 + j]); }
    unsigned short* dp = dst + (long)(n0 + r2) * 512 + by * 64 + c2;
    *reinterpret_cast<bf16x8*>(dp)     = o0.v;
    *reinterpret_cast<bf16x8*>(dp + 8) = o1.v;
}

// ---------------------------------------------------------------------------
// E[h][n][m] = mask ? bf16(exp(scale*q_h[n]·k_h[m])) : 0.
// Block = (16 n-rows, head); grid (128, 8). Wave owns a 512-m quarter,
// q-frags persist in registers, 64 MFMA/block, no barriers.
// Epilogue: wave-private padded LDS, read back row-major -> every store is
// two fully covered 512B row segments (no partial-line amplification).
// ---------------------------------------------------------------------------
__global__ __launch_bounds__(256)
void scores_rows(const unsigned short* __restrict__ qh,
                 const unsigned short* __restrict__ kh,
                 const unsigned char* __restrict__ mby,
                 const float* __restrict__ tptr,
                 unsigned short* __restrict__ Ebf)
{
    const int h  = blockIdx.y;
    const int n0 = blockIdx.x * 16;
    const int tid = threadIdx.x;
    const int wv = tid >> 6;
    const int lane = tid & 63;
    const float scale = 1.0f / (8.0f * tptr[0]);

    __shared__ unsigned short lsb[4][16][260];

    const int arow = lane & 15;
    const int koct = (lane >> 4) * 8;
    const unsigned short* Aq = qh + (long)(n0 + arow) * 512 + h * 64;
    const bf16x8 aq0 = *reinterpret_cast<const bf16x8*>(Aq + koct);
    const bf16x8 aq1 = *reinterpret_cast<const bf16x8*>(Aq + 32 + koct);

    const int lr = (lane >> 4) * 4;
    const int lc = lane & 15;
    const int rlo = lane >> 5;
    const int cch = lane & 31;

#pragma unroll
    for (int half = 0; half < 2; half++) {
        const int mbase = wv * 512 + half * 256;
#pragma unroll
        for (int mt = 0; mt < 16; mt++) {
            const unsigned short* Bk = kh + (long)(mbase + mt * 16 + arow) * 512 + h * 64;
            bf16x8 b0 = *reinterpret_cast<const bf16x8*>(Bk + koct);
            bf16x8 b1 = *reinterpret_cast<const bf16x8*>(Bk + 32 + koct);
            f32x4 c = {};
            c = __builtin_amdgcn_mfma_f32_16x16x32_bf16(aq0, b0, c, 0, 0, 0);
            c = __builtin_amdgcn_mfma_f32_16x16x32_bf16(aq1, b1, c, 0, 0, 0);
#pragma unroll
            for (int r = 0; r < 4; r++)
                lsb[wv][lr + r][mt * 16 + lc] = f2bf(__expf(c[r] * scale));
        }
#pragma unroll
        for (int rp = 0; rp < 8; rp++) {
            const int row = rp * 2 + rlo;
            const int gn = n0 + row;
            const int m = mbase + cch * 8;
            EU e;
            e.v = *reinterpret_cast<const bf16x8*>(&lsb[wv][row][cch * 8]);
            unsigned long long mk =
                *reinterpret_cast<const unsigned long long*>(mby + (long)gn * 2048 + m);
            EU o;
#pragma unroll
            for (int j = 0; j < 8; j++)
                o.u[j] = ((mk >> (8 * j)) & 0xff) ? e.u[j] : (unsigned short)0;
            *reinterpret_cast<bf16x8*>(Ebf + ((long)h * 2048 + gn) * 2048 + m) = o.v;
        }
    }
}

// ---------------------------------------------------------------------------
// One mean-shift iteration. Block = 4 rows (1024 threads, 4 row-groups of
// 256), grid 512. 4x the E loads in flight per block; barriers amortized.
// Thread owns m = t*8..+8 for all 8 heads of its row. Last iter (wlast)
// stores g (bf16, 8 MB) and invz (fp32 [h][n]); attn never materialized.
// ---------------------------------------------------------------------------
__global__ __launch_bounds__(1024)
void ms_iter(const unsigned short* __restrict__ Ebf,
             const float* __restrict__ xyz_src,
             float* __restrict__ xyz_dst,
             const float* __restrict__ y_hat,
             const float* __restrict__ bwp,
             unsigned short* __restrict__ gbf,
             float* __restrict__ invzb,
             int wlast)
{
    const int tid = threadIdx.x;
    const int rg  = tid >> 8;          // row group 0..3
    const int t   = tid & 255;
    const int n   = blockIdx.x * 4 + rg;
    const int lane = tid & 63;
    const int wv4 = (t >> 6) & 3;      // wave within group
    const int m0 = t * 8;

    __shared__ float red[4][52];

    // E loads first (max memory-level parallelism)
    EU E[8];
    const unsigned short* Ep = Ebf + (long)n * 2048 + m0;
#pragma unroll
    for (int h = 0; h < 8; h++)
        E[h].v = *reinterpret_cast<const bf16x8*>(Ep + (long)h * 4194304);

    const float bw = bwp[0];
    const float c2k = 1.0f / (2.0f * bw * bw);
    const float xn = xyz_src[n * 3 + 0];
    const float yn = xyz_src[n * 3 + 1];
    const float zn = xyz_src[n * 3 + 2];
    const float sqn = xn * xn + yn * yn + zn * zn;

    // g for this thread's 8 m's (coords not kept live past this block)
    float g[8];
    {
        const float4* xp = reinterpret_cast<const float4*>(xyz_src + (long)m0 * 3);
        float4 a = xp[0], b = xp[1], c = xp[2], d = xp[3], e = xp[4], f = xp[5];
        float mx[8], my[8], mz[8];
        mx[0]=a.x; my[0]=a.y; mz[0]=a.z;  mx[1]=a.w; my[1]=b.x; mz[1]=b.y;
        mx[2]=b.z; my[2]=b.w; mz[2]=c.x;  mx[3]=c.y; my[3]=c.z; mz[3]=c.w;
        mx[4]=d.x; my[4]=d.y; mz[4]=d.z;  mx[5]=d.w; my[5]=e.x; mz[5]=e.y;
        mx[6]=e.z; my[6]=e.w; mz[6]=f.x;  mx[7]=f.y; my[7]=f.z; mz[7]=f.w;
        float4 yh0 = *reinterpret_cast<const float4*>(y_hat + m0);
        float4 yh1 = *reinterpret_cast<const float4*>(y_hat + m0 + 4);
        float yh[8] = {yh0.x, yh0.y, yh0.z, yh0.w, yh1.x, yh1.y, yh1.z, yh1.w};
#pragma unroll
        for (int j = 0; j < 8; j++) {
            const float d2 = sqn + (mx[j]*mx[j] + my[j]*my[j] + mz[j]*mz[j])
                           - 2.0f * (xn*mx[j] + yn*my[j] + zn*mz[j]);
            g[j] = __expf(-d2 * c2k) * yh[j] + 1e-9f;
        }
    }

    float z[8];
#pragma unroll
    for (int h = 0; h < 8; h++) {
        float zz = 0.f;
#pragma unroll
        for (int j = 0; j < 8; j++) zz += bf2f(E[h].u[j]) * g[j];
        z[h] = zz;
    }

#pragma unroll
    for (int h = 0; h < 8; h++) {
        float v = z[h];
#pragma unroll
        for (int off = 32; off > 0; off >>= 1) v += __shfl_down(v, off, 64);
        if (lane == 0) red[rg][wv4 * 8 + h] = v;
    }
    __syncthreads();
    if (t < 8) {
        const float s = red[rg][t] + red[rg][8 + t] + red[rg][16 + t] + red[rg][24 + t];
        const float iz = 1.0f / s;
        red[rg][32 + t] = iz;
        if (wlast) invzb[t * 2048 + n] = iz;
    }
    __syncthreads();
    float invz[8];
#pragma unroll
    for (int h = 0; h < 8; h++) invz[h] = red[rg][32 + h];

    // pass 2: reload coords (L1-hot), accumulate xyz update
    float ax = 0.f, ay = 0.f, az = 0.f;
    {
        const float4* xp = reinterpret_cast<const float4*>(xyz_src + (long)m0 * 3);
        float4 a = xp[0], b = xp[1], c = xp[2], d = xp[3], e = xp[4], f = xp[5];
        float mx[8], my[8], mz[8];
        mx[0]=a.x; my[0]=a.y; mz[0]=a.z;  mx[1]=a.w; my[1]=b.x; mz[1]=b.y;
        mx[2]=b.z; my[2]=b.w; mz[2]=c.x;  mx[3]=c.y; my[3]=c.z; mz[3]=c.w;
        mx[4]=d.x; my[4]=d.y; mz[4]=d.z;  mx[5]=d.w; my[5]=e.x; mz[5]=e.y;
        mx[6]=e.z; my[6]=e.w; mz[6]=f.x;  mx[7]=f.y; my[7]=f.z; mz[7]=f.w;
#pragma unroll
        for (int j = 0; j < 8; j++) {
            float w = 0.f;
#pragma unroll
            for (int h = 0; h < 8; h++) w += bf2f(E[h].u[j]) * invz[h];
            w *= 0.125f * g[j];
            ax += w * mx[j]; ay += w * my[j]; az += w * mz[j];
        }
    }
    if (wlast) {
        EU og;
#pragma unroll
        for (int j = 0; j < 8; j++) og.u[j] = f2bf(g[j]);
        *reinterpret_cast<bf16x8*>(gbf + (long)n * 2048 + m0) = og.v;
    }

    float v3[3] = {ax, ay, az};
#pragma unroll
    for (int c = 0; c < 3; c++) {
        float v = v3[c];
#pragma unroll
        for (int off = 32; off > 0; off >>= 1) v += __shfl_down(v, off, 64);
        if (lane == 0) red[rg][40 + c * 4 + wv4] = v;   // distinct slots: no WAR
    }
    __syncthreads();
    if (t < 3) {
        xyz_dst[n * 3 + t] = red[rg][40 + t * 4 + 0] + red[rg][40 + t * 4 + 1] +
                             red[rg][40 + t * 4 + 2] + red[rg][40 + t * 4 + 3];
    }
}

// ---------------------------------------------------------------------------
// x_partial = (E⊙g) @ v via MFMA bf16, register-fused A, double-buffered
// A/g loads. grid (32 n-tiles, 8 K-splits, 8 heads) = 2048 blocks.
// Each K-split writes its own fp32 partial plane (non-atomic).
// ---------------------------------------------------------------------------
__global__ __launch_bounds__(256)
void av_mfma(const unsigned short* __restrict__ Ebf,   // [8][2048][2048]
             const unsigned short* __restrict__ gbf,   // [2048][2048]
             const unsigned short* __restrict__ vT,    // [512][2048]
             float* __restrict__ P)                    // [8][2048][512]
{
    const int h  = blockIdx.z;
    const int s  = blockIdx.y;
    const int bx = blockIdx.x;
    const int wv = threadIdx.x >> 6;
    const int lane = threadIdx.x & 63;
    const int n0 = bx * 64 + wv * 16;
    const int kc = s * 256;

    const int mrow = lane & 15;
    const int koct = (lane >> 4) * 8;

    const unsigned short* Ab = Ebf + ((long)h * 2048 + n0 + mrow) * 2048 + kc + koct;
    const unsigned short* Gb = gbf + (long)(n0 + mrow) * 2048 + kc + koct;
    const unsigned short* Bb = vT + ((long)h * 64 + mrow) * 2048 + kc + koct;

    f32x4 acc[4] = {};
    EU e0, g0;
    e0.v = *reinterpret_cast<const bf16x8*>(Ab);
    g0.v = *reinterpret_cast<const bf16x8*>(Gb);
#pragma unroll
    for (int ki = 0; ki < 8; ki++) {
        EU e1, g1;
        if (ki < 7) {
            e1.v = *reinterpret_cast<const bf16x8*>(Ab + (ki + 1) * 32);
            g1.v = *reinterpret_cast<const bf16x8*>(Gb + (ki + 1) * 32);
        }
        EU a;
#pragma unroll
        for (int j = 0; j < 8; j++)
            a.u[j] = f2bf(bf2f(e0.u[j]) * bf2f(g0.u[j]));
#pragma unroll
        for (int t = 0; t < 4; t++) {
            bf16x8 b = *reinterpret_cast<const bf16x8*>(Bb + (long)(t * 16) * 2048 + ki * 32);
            acc[t] = __builtin_amdgcn_mfma_f32_16x16x32_bf16(a.v, b, acc[t], 0, 0, 0);
        }
        e0 = e1; g0 = g1;
    }

    float* Pp = P + (long)s * 1048576;
    const int rbase = n0 + (lane >> 4) * 4;
    const int dcol = lane & 15;
#pragma unroll
    for (int t = 0; t < 4; t++)
#pragma unroll
        for (int r = 0; r < 4; r++)
            Pp[(long)(rbase + r) * 512 + h * 64 + t * 16 + dcol] = acc[t][r];
}

// ---------------------------------------------------------------------------
// xc[n][d] bf16 = invz_h[n] * sum of 8 fp32 partials. 8 elems/thread.
// ---------------------------------------------------------------------------
__global__ __launch_bounds__(256)
void av_red(const float* __restrict__ P, const float* __restrict__ invzb,
            unsigned short* __restrict__ xc)
{
    const long idx = (long)(blockIdx.x * 256 + threadIdx.x) * 8;
    const int n = (int)(idx >> 9);
    const int d0 = (int)(idx & 511);
    const float iz = invzb[(d0 >> 6) * 2048 + n];
    float s[8] = {};
#pragma unroll
    for (int p = 0; p < 8; p++) {
        const float* pp = P + (long)p * 1048576 + idx;
        float4 a = *reinterpret_cast<const float4*>(pp);
        float4 b = *reinterpret_cast<const float4*>(pp + 4);
        s[0] += a.x; s[1] += a.y; s[2] += a.z; s[3] += a.w;
        s[4] += b.x; s[5] += b.y; s[6] += b.z; s[7] += b.w;
    }
    EU o;
#pragma unroll
    for (int j = 0; j < 8; j++) o.u[j] = f2bf(s[j] * iz);
    *reinterpret_cast<bf16x8*>(xc + idx) = o.v;
}

// ---------------------------------------------------------------------------
// out = xc @ Wo.T + bo via bf16 MFMA, fp32 out. grid (32 n-tiles, 8 d-tiles).
// ---------------------------------------------------------------------------
__global__ __launch_bounds__(256)
void out_mfma(const unsigned short* __restrict__ xc,
              const unsigned short* __restrict__ sW,   // seg 3 = Wo
              const float* __restrict__ bo,
              float* __restrict__ out)
{
    const int bx = blockIdx.x;
    const int by = blockIdx.y;
    const int wv = threadIdx.x >> 6;
    const int lane = threadIdx.x & 63;
    const int row  = lane & 15;
    const int koct = (lane >> 4) * 8;
    const int n0 = bx * 64;

    const unsigned short* Ap = xc + (long)(n0 + wv * 16 + row) * 512;
    const unsigned short* Bp = sW + 3L * 262144 + (long)(by * 64 + row) * 512;

    f32x4 acc[4] = {};
#pragma unroll
    for (int k0 = 0; k0 < 512; k0 += 32) {
        bf16x8 a = *reinterpret_cast<const bf16x8*>(Ap + k0 + koct);
#pragma unroll
        for (int t = 0; t < 4; t++) {
            bf16x8 b = *reinterpret_cast<const bf16x8*>(Bp + (long)(t * 16) * 512 + k0 + koct);
            acc[t] = __builtin_amdgcn_mfma_f32_16x16x32_bf16(a, b, acc[t], 0, 0, 0);
        }
    }

    const int rbase = n0 + wv * 16 + (lane >> 4) * 4;
    const int dcol = lane & 15;
#pragma unroll
    for (int t = 0; t < 4; t++) {
        const int col = by * 64 + t * 16 + dcol;
        const float bb = bo[col];
#pragma unroll
        for (int r = 0; r < 4; r++)
            out[(long)(rbase + r) * 512 + col] = acc[t][r] + bb;
    }
}

// ---------------------------------------------------------------------------
extern "C" void kernel_launch(void* const* d_in, const int* in_sizes, int n_in,
                              void* d_out, int out_size, void* d_ws, size_t ws_size,
                              hipStream_t stream)
{
    (void)in_sizes; (void)n_in; (void)out_size; (void)ws_size;

    const float* xyz   = (const float*)d_in[0];
    const float* strf  = (const float*)d_in[1];
    // d_in[2] esm_feat: dead code (DCE'd in reference)
    const float* yhat  = (const float*)d_in[3];
    const int*   dmask = (const int*)d_in[4];
    const float* tptr  = (const float*)d_in[5];
    const float* bwptr = (const float*)d_in[6];
    // d_in[7] max_iter = 5 (fixed)
    const float* Wq = (const float*)d_in[8];
    const float* bq = (const float*)d_in[9];
    const float* Wk = (const float*)d_in[10];
    const float* bk = (const float*)d_in[11];
    const float* Wv = (const float*)d_in[12];
    const float* bv = (const float*)d_in[13];
    const float* Wo = (const float*)d_in[14];
    const float* bo = (const float*)d_in[15];
    float* outp = (float*)d_out;

    char* wsb = (char*)d_ws;
    float* Ppart         = (float*)(wsb);                        // [8][2048][512] f32, 32 MB
    unsigned short* xc   = (unsigned short*)(wsb + (32L << 20)); // 2 MB
    unsigned short* sA   = (unsigned short*)(wsb + (34L << 20)); // 2 MB
    unsigned short* sW   = (unsigned short*)(wsb + (36L << 20)); // [4][262144] bf16, 2 MB
    unsigned short* qh   = (unsigned short*)(wsb + (38L << 20)); // 2 MB
    unsigned short* kh   = (unsigned short*)(wsb + (40L << 20)); // 2 MB
    unsigned short* vT   = (unsigned short*)(wsb + (42L << 20)); // 2 MB
    float* xyzA          = (float*)(wsb + (44L << 20));
    float* xyzB          = xyzA + 8192;
    unsigned char* mby   = (unsigned char*)(wsb + (45L << 20));  // 4 MB
    unsigned short* Ebf  = (unsigned short*)(wsb + (49L << 20)); // [8][2048][2048] bf16, 64 MB
    unsigned short* gbf  = (unsigned short*)(wsb + (113L << 20)); // [2048][2048] bf16, 8 MB
    float* invzb         = (float*)(wsb + (121L << 20));         // [8][2048] f32, 64 KB

    dim3 blk(256, 1, 1);

    // bf16 conversions (incl. Wo) + byte mask + q/k/v MFMA projections
    conv_all<<<dim3(3072), blk, 0, stream>>>(strf, Wq, Wk, Wv, Wo, dmask, sA, sW, mby);
    qkv_mfma<<<dim3(32, 8, 3), blk, 0, stream>>>(sA, sW, bq, bk, bv, qh, kh, vT);

    // E = mask ? exp(q·k/(8t)) : 0, bf16, [h][n][m], coalesced row stores
    scores_rows<<<dim3(128, 8), blk, 0, stream>>>(qh, kh, mby, tptr, Ebf);

    // 5 mean-shift iterations (4 rows per 1024-thread block); last stores g+invz
    const float* src = xyz;
    float* dsts[5] = {xyzA, xyzB, xyzA, xyzB, outp};
    for (int it = 0; it < 5; it++) {
        ms_iter<<<dim3(512), dim3(1024), 0, stream>>>(Ebf, src, dsts[it], yhat, bwptr,
                                                      gbf, invzb, it == 4 ? 1 : 0);
        src = dsts[it];
    }

    // x = (E⊙g) @ v (register-fused A, K-split 8), reduce*invz, out-proj
    av_mfma<<<dim3(32, 8, 8), blk, 0, stream>>>(Ebf, gbf, vT, Ppart);
    av_red<<<dim3(512), blk, 0, stream>>>(Ppart, invzb, xc);
    out_mfma<<<dim3(32, 8), blk, 0, stream>>>(xc, sW, bo, outp + 6144);
}

// Round 12
// 318.551 us; speedup vs baseline: 1.0745x; 1.0745x over previous
//
#include <hip/hip_runtime.h>

// Problem constants (fixed by setup_inputs): N=2048, D=512, H=8, dh=64, max_iter=5.
// Identity: exp(s/t + log(kern*yw+eps)) = exp(s/t) * (kern*yw+eps).
// E[h][n][m] = mask ? bf16(exp(s/(8t))) : 0 is loop-invariant (64 MB).
// ms_iter stages its 32 KB E row-set into LDS via global_load_lds (async,
// 128 KB in flight per CU) -> targets the bytes-in-flight deficit that capped
// all E-streaming kernels at ~1.7 TB/s. attn never materialized: last iter
// stores g (bf16) + invz; av fuses A = E*g during LDS staging.

typedef __attribute__((ext_vector_type(8))) short bf16x8;
typedef __attribute__((ext_vector_type(4))) float f32x4;

__device__ __forceinline__ unsigned short f2bf(float f) {
    unsigned int u = __float_as_uint(f);
    u += 0x7fff + ((u >> 16) & 1);   // RNE (inputs finite)
    return (unsigned short)(u >> 16);
}
__device__ __forceinline__ float bf2f(unsigned short u) {
    return __uint_as_float((unsigned int)u << 16);
}

union EU { bf16x8 v; unsigned short u[8]; };

// ---------------------------------------------------------------------------
// Convert strf + Wq/Wk/Wv/Wo fp32->bf16 (sW = [4][262144]) and dmask->byte.
// 8 elems/thread; grid 3072x256 exact.
// ---------------------------------------------------------------------------
__global__ __launch_bounds__(256)
void conv_all(const float* __restrict__ strf,
              const float* __restrict__ Wq, const float* __restrict__ Wk,
              const float* __restrict__ Wv, const float* __restrict__ Wo,
              const int* __restrict__ dmask,
              unsigned short* __restrict__ sA, unsigned short* __restrict__ sW,
              unsigned char* __restrict__ mby)
{
    const long base = (long)(blockIdx.x * 256 + threadIdx.x) * 8;
    if (base >= 2097152) {
        const long rel = base - 2097152;
        int4 a = *reinterpret_cast<const int4*>(dmask + rel);
        int4 b = *reinterpret_cast<const int4*>(dmask + rel + 4);
        unsigned long long p = 0;
        p |= (a.x > 0) ? 0x01ULL : 0;  p |= (a.y > 0) ? 0x0100ULL : 0;
        p |= (a.z > 0) ? 0x010000ULL : 0;  p |= (a.w > 0) ? 0x01000000ULL : 0;
        p |= (b.x > 0) ? 0x0100000000ULL : 0;  p |= (b.y > 0) ? 0x010000000000ULL : 0;
        p |= (b.z > 0) ? 0x01000000000000ULL : 0;  p |= (b.w > 0) ? 0x0100000000000000ULL : 0;
        *reinterpret_cast<unsigned long long*>(mby + rel) = p;
        return;
    }
    const float* src;
    unsigned short* dst;
    if (base < 1048576) {
        src = strf + base; dst = sA + base;
    } else {
        const long rel = base - 1048576;
        const int seg = (int)(rel >> 18);
        const long off = rel & 262143;
        const float* Ws[4] = {Wq, Wk, Wv, Wo};
        src = Ws[seg] + off;
        dst = sW + (long)seg * 262144 + off;
    }
    float4 a = *reinterpret_cast<const float4*>(src);
    float4 b = *reinterpret_cast<const float4*>(src + 4);
    EU o;
    o.u[0] = f2bf(a.x); o.u[1] = f2bf(a.y); o.u[2] = f2bf(a.z); o.u[3] = f2bf(a.w);
    o.u[4] = f2bf(b.x); o.u[5] = f2bf(b.y); o.u[6] = f2bf(b.z); o.u[7] = f2bf(b.w);
    *reinterpret_cast<bf16x8*>(dst) = o.v;
}

// ---------------------------------------------------------------------------
// q/k/v projection via bf16 MFMA. grid (32 n-tiles, 8 d-tiles, 3).
// z=0 -> qh, z=1 -> kh, z=2 -> vT (transposed direct store).
// ---------------------------------------------------------------------------
__global__ __launch_bounds__(256)
void qkv_mfma(const unsigned short* __restrict__ sA,
              const unsigned short* __restrict__ sW,
              const float* __restrict__ bq, const float* __restrict__ bk,
              const float* __restrict__ bv,
              unsigned short* __restrict__ qh, unsigned short* __restrict__ kh,
              unsigned short* __restrict__ vT)
{
    const int z  = blockIdx.z;
    const int bx = blockIdx.x;
    const int by = blockIdx.y;
    const int tid = threadIdx.x;
    const int wv = tid >> 6;
    const int lane = tid & 63;
    const int row  = lane & 15;
    const int koct = (lane >> 4) * 8;
    const int n0 = bx * 64;

    const unsigned short* Ap = sA + (long)(n0 + wv * 16 + row) * 512;
    const unsigned short* Bp = sW + (long)z * 262144 + (long)(by * 64 + row) * 512;

    f32x4 acc[4] = {};
#pragma unroll
    for (int k0 = 0; k0 < 512; k0 += 32) {
        bf16x8 a = *reinterpret_cast<const bf16x8*>(Ap + k0 + koct);
#pragma unroll
        for (int t = 0; t < 4; t++) {
            bf16x8 b = *reinterpret_cast<const bf16x8*>(Bp + (long)(t * 16) * 512 + k0 + koct);
            acc[t] = __builtin_amdgcn_mfma_f32_16x16x32_bf16(a, b, acc[t], 0, 0, 0);
        }
    }

    if (z == 2) {
        const int rbase = n0 + wv * 16 + (lane >> 4) * 4;
#pragma unroll
        for (int t = 0; t < 4; t++) {
            const int d = by * 64 + t * 16 + (lane & 15);
            const float bb = bv[d];
            ushort4 o;
            o.x = f2bf(acc[t][0] + bb); o.y = f2bf(acc[t][1] + bb);
            o.z = f2bf(acc[t][2] + bb); o.w = f2bf(acc[t][3] + bb);
            *reinterpret_cast<ushort4*>(vT + (long)d * 2048 + rbase) = o;
        }
        return;
    }

    __shared__ float ls[64][68];
    const int lrb = wv * 16 + (lane >> 4) * 4;
    const int lcb = lane & 15;
#pragma unroll
    for (int t = 0; t < 4; t++)
#pragma unroll
        for (int r = 0; r < 4; r++)
            ls[lrb + r][t * 16 + lcb] = acc[t][r];
    __syncthreads();

    const float* bias = (z == 0) ? bq : bk;
    unsigned short* dst = (z == 0) ? qh : kh;
    const int r2 = tid >> 2;
    const int c2 = (tid & 3) * 16;
    float sv[16];
#pragma unroll
    for (int j = 0; j < 4; j++) {
        float4 s = *reinterpret_cast<const float4*>(&ls[r2][c2 + j * 4]);
        float4 bb = *reinterpret_cast<const float4*>(bias + by * 64 + c2 + j * 4);
        sv[j*4+0] = s.x + bb.x; sv[j*4+1] = s.y + bb.y;
        sv[j*4+2] = s.z + bb.z; sv[j*4+3] = s.w + bb.w;
    }
    EU o0, o1;
#pragma unroll
    for (int j = 0; j < 8; j++) { o0.u[j] = f2bf(sv[j]); o1.u[j] = f2bf(sv[8 + j]); }
    unsigned short* dp = dst + (long)(n0 + r2) * 512 + by * 64 + c2;
    *reinterpret_cast<bf16x8*>(dp)     = o0.v;
    *reinterpret_cast<bf16x8*>(dp + 8) = o1.v;
}

// ---------------------------------------------------------------------------
// E[h][n][m] = mask ? bf16(exp(scale*q_h[n]·k_h[m])) : 0.
// Block = (16 n-rows, head); grid (128, 8). Wave owns a 512-m quarter,
// q-frags persist in registers, 64 MFMA/block, no barriers.
// Epilogue: wave-private padded LDS, read back row-major -> every store is
// two fully covered 512B row segments (no partial-line amplification).
// ---------------------------------------------------------------------------
__global__ __launch_bounds__(256)
void scores_rows(const unsigned short* __restrict__ qh,
                 const unsigned short* __restrict__ kh,
                 const unsigned char* __restrict__ mby,
                 const float* __restrict__ tptr,
                 unsigned short* __restrict__ Ebf)
{
    const int h  = blockIdx.y;
    const int n0 = blockIdx.x * 16;
    const int tid = threadIdx.x;
    const int wv = tid >> 6;
    const int lane = tid & 63;
    const float scale = 1.0f / (8.0f * tptr[0]);

    __shared__ unsigned short lsb[4][16][260];

    const int arow = lane & 15;
    const int koct = (lane >> 4) * 8;
    const unsigned short* Aq = qh + (long)(n0 + arow) * 512 + h * 64;
    const bf16x8 aq0 = *reinterpret_cast<const bf16x8*>(Aq + koct);
    const bf16x8 aq1 = *reinterpret_cast<const bf16x8*>(Aq + 32 + koct);

    const int lr = (lane >> 4) * 4;
    const int lc = lane & 15;
    const int rlo = lane >> 5;
    const int cch = lane & 31;

#pragma unroll
    for (int half = 0; half < 2; half++) {
        const int mbase = wv * 512 + half * 256;
#pragma unroll
        for (int mt = 0; mt < 16; mt++) {
            const unsigned short* Bk = kh + (long)(mbase + mt * 16 + arow) * 512 + h * 64;
            bf16x8 b0 = *reinterpret_cast<const bf16x8*>(Bk + koct);
            bf16x8 b1 = *reinterpret_cast<const bf16x8*>(Bk + 32 + koct);
            f32x4 c = {};
            c = __builtin_amdgcn_mfma_f32_16x16x32_bf16(aq0, b0, c, 0, 0, 0);
            c = __builtin_amdgcn_mfma_f32_16x16x32_bf16(aq1, b1, c, 0, 0, 0);
#pragma unroll
            for (int r = 0; r < 4; r++)
                lsb[wv][lr + r][mt * 16 + lc] = f2bf(__expf(c[r] * scale));
        }
#pragma unroll
        for (int rp = 0; rp < 8; rp++) {
            const int row = rp * 2 + rlo;
            const int gn = n0 + row;
            const int m = mbase + cch * 8;
            EU e;
            e.v = *reinterpret_cast<const bf16x8*>(&lsb[wv][row][cch * 8]);
            unsigned long long mk =
                *reinterpret_cast<const unsigned long long*>(mby + (long)gn * 2048 + m);
            EU o;
#pragma unroll
            for (int j = 0; j < 8; j++)
                o.u[j] = ((mk >> (8 * j)) & 0xff) ? e.u[j] : (unsigned short)0;
            *reinterpret_cast<bf16x8*>(Ebf + ((long)h * 2048 + gn) * 2048 + m) = o.v;
        }
    }
}

// ---------------------------------------------------------------------------
// One mean-shift iteration. Block = row n, 256 threads. E row-set (32 KB)
// staged into LDS via async global_load_lds (1 KB per (h,wave) instruction),
// overlapped with the g/exp computation; then z and the xyz update read LDS.
// Last iter (wlast) stores g (bf16, 8 MB) and invz (fp32 [h][n]).
// ---------------------------------------------------------------------------
__global__ __launch_bounds__(256)
void ms_iter(const unsigned short* __restrict__ Ebf,
             const float* __restrict__ xyz_src,
             float* __restrict__ xyz_dst,
             const float* __restrict__ y_hat,
             const float* __restrict__ bwp,
             unsigned short* __restrict__ gbf,
             float* __restrict__ invzb,
             int wlast)
{
    const int n = blockIdx.x;
    const int tid = threadIdx.x;
    const int lane = tid & 63;
    const int wave = tid >> 6;
    const int m0 = tid * 8;          // = wave*512 + lane*8

    __shared__ unsigned short Es[8][4][512];   // 32 KB
    __shared__ float red[64];

    // fire-and-forget: stage E[h][n][wave*512 .. +512] -> Es[h][wave][:]
    {
        const unsigned short* gp = Ebf + (long)n * 2048 + wave * 512 + lane * 8;
#pragma unroll
        for (int h = 0; h < 8; h++) {
            __builtin_amdgcn_global_load_lds(
                (const __attribute__((address_space(1))) unsigned int*)(gp + (long)h * 4194304),
                (__attribute__((address_space(3))) unsigned int*)&Es[h][wave][0],
                16, 0, 0);
        }
    }

    const float bw = bwp[0];
    const float c2k = 1.0f / (2.0f * bw * bw);
    const float xn = xyz_src[n * 3 + 0];
    const float yn = xyz_src[n * 3 + 1];
    const float zn = xyz_src[n * 3 + 2];
    const float sqn = xn * xn + yn * yn + zn * zn;

    float mx[8], my[8], mz[8];
    {
        const float4* xp = reinterpret_cast<const float4*>(xyz_src + (long)m0 * 3);
        float4 a = xp[0], b = xp[1], c = xp[2], d = xp[3], e = xp[4], f = xp[5];
        mx[0]=a.x; my[0]=a.y; mz[0]=a.z;  mx[1]=a.w; my[1]=b.x; mz[1]=b.y;
        mx[2]=b.z; my[2]=b.w; mz[2]=c.x;  mx[3]=c.y; my[3]=c.z; mz[3]=c.w;
        mx[4]=d.x; my[4]=d.y; mz[4]=d.z;  mx[5]=d.w; my[5]=e.x; mz[5]=e.y;
        mx[6]=e.z; my[6]=e.w; mz[6]=f.x;  mx[7]=f.y; my[7]=f.z; mz[7]=f.w;
    }
    float4 yh0 = *reinterpret_cast<const float4*>(y_hat + m0);
    float4 yh1 = *reinterpret_cast<const float4*>(y_hat + m0 + 4);
    float yh[8] = {yh0.x, yh0.y, yh0.z, yh0.w, yh1.x, yh1.y, yh1.z, yh1.w};

    float g[8];
#pragma unroll
    for (int j = 0; j < 8; j++) {
        const float d2 = sqn + (mx[j]*mx[j] + my[j]*my[j] + mz[j]*mz[j])
                       - 2.0f * (xn*mx[j] + yn*my[j] + zn*mz[j]);
        g[j] = __expf(-d2 * c2k) * yh[j] + 1e-9f;
    }

    __syncthreads();   // drains vmcnt (global_load_lds) for all waves

    EU E[8];
#pragma unroll
    for (int h = 0; h < 8; h++)
        E[h].v = *reinterpret_cast<const bf16x8*>(&Es[h][wave][lane * 8]);

    float z[8];
#pragma unroll
    for (int h = 0; h < 8; h++) {
        float zz = 0.f;
#pragma unroll
        for (int j = 0; j < 8; j++) zz += bf2f(E[h].u[j]) * g[j];
        z[h] = zz;
    }

#pragma unroll
    for (int h = 0; h < 8; h++) {
        float v = z[h];
#pragma unroll
        for (int off = 32; off > 0; off >>= 1) v += __shfl_down(v, off, 64);
        if (lane == 0) red[wave * 8 + h] = v;
    }
    __syncthreads();
    if (tid < 8) {
        const float s = red[tid] + red[8 + tid] + red[16 + tid] + red[24 + tid];
        const float iz = 1.0f / s;
        red[32 + tid] = iz;
        if (wlast) invzb[tid * 2048 + n] = iz;
    }
    __syncthreads();
    float invz[8];
#pragma unroll
    for (int h = 0; h < 8; h++) invz[h] = red[32 + h];

    float ax = 0.f, ay = 0.f, az = 0.f;
#pragma unroll
    for (int j = 0; j < 8; j++) {
        float w = 0.f;
#pragma unroll
        for (int h = 0; h < 8; h++) w += bf2f(E[h].u[j]) * invz[h];
        w *= 0.125f * g[j];
        ax += w * mx[j]; ay += w * my[j]; az += w * mz[j];
    }
    if (wlast) {
        EU og;
#pragma unroll
        for (int j = 0; j < 8; j++) og.u[j] = f2bf(g[j]);
        *reinterpret_cast<bf16x8*>(gbf + (long)n * 2048 + m0) = og.v;
    }

    float v3[3] = {ax, ay, az};
#pragma unroll
    for (int c = 0; c < 3; c++) {
        float v = v3[c];
#pragma unroll
        for (int off = 32; off > 0; off >>= 1) v += __shfl_down(v, off, 64);
        if (lane == 0) red[40 + c * 4 + wave] = v;
    }
    __syncthreads();
    if (tid < 3) {
        xyz_dst[n * 3 + tid] = red[40 + tid * 4 + 0] + red[40 + tid * 4 + 1] +
                               red[40 + tid * 4 + 2] + red[40 + tid * 4 + 3];
    }
}

// ---------------------------------------------------------------------------
// x_partial = (E⊙g) @ v via MFMA bf16, A fused during LDS staging (R7 form).
// grid (32 n-tiles, 4 K-splits, 8 heads). A-tile 64x128, coalesced 256B
// row reads, LDS pad 132 -> conflict-free frag reads. fp32 partial planes.
// ---------------------------------------------------------------------------
__global__ __launch_bounds__(256)
void av_mfma(const unsigned short* __restrict__ Ebf,   // [8][2048][2048]
             const unsigned short* __restrict__ gbf,   // [2048][2048]
             const unsigned short* __restrict__ vT,    // [512][2048]
             float* __restrict__ P)                    // [4][2048][512]
{
    const int h  = blockIdx.z;
    const int s  = blockIdx.y;
    const int bx = blockIdx.x;
    const int tid = threadIdx.x;
    const int wv = tid >> 6;
    const int lane = tid & 63;
    const int n0 = bx * 64;
    const int kc = s * 512;

    __shared__ unsigned short As[64][132];

    const int mrow = lane & 15;
    const int koct = (lane >> 4) * 8;
    const int srow = tid >> 4;
    const int skk  = (tid & 15) * 8;

    f32x4 acc[4] = {};
    for (int kt = 0; kt < 4; kt++) {
        const int kb = kc + kt * 128;
        __syncthreads();
#pragma unroll
        for (int l = 0; l < 4; l++) {
            const int row = l * 16 + srow;
            EU e, gg;
            e.v  = *reinterpret_cast<const bf16x8*>(Ebf + ((long)h * 2048 + n0 + row) * 2048 + kb + skk);
            gg.v = *reinterpret_cast<const bf16x8*>(gbf + (long)(n0 + row) * 2048 + kb + skk);
            EU a;
#pragma unroll
            for (int j = 0; j < 8; j++)
                a.u[j] = f2bf(bf2f(e.u[j]) * bf2f(gg.u[j]));
            *reinterpret_cast<bf16x8*>(&As[row][skk]) = a.v;
        }
        __syncthreads();
#pragma unroll
        for (int k2 = 0; k2 < 128; k2 += 32) {
            bf16x8 a = *reinterpret_cast<const bf16x8*>(&As[wv * 16 + mrow][k2 + koct]);
#pragma unroll
            for (int t = 0; t < 4; t++) {
                bf16x8 b = *reinterpret_cast<const bf16x8*>(
                    vT + ((long)h * 64 + t * 16 + mrow) * 2048 + kb + k2 + koct);
                acc[t] = __builtin_amdgcn_mfma_f32_16x16x32_bf16(a, b, acc[t], 0, 0, 0);
            }
        }
    }

    float* Pp = P + (long)s * 1048576;
    const int rbase = n0 + wv * 16 + (lane >> 4) * 4;
    const int dcol = lane & 15;
#pragma unroll
    for (int t = 0; t < 4; t++)
#pragma unroll
        for (int r = 0; r < 4; r++)
            Pp[(long)(rbase + r) * 512 + h * 64 + t * 16 + dcol] = acc[t][r];
}

// ---------------------------------------------------------------------------
// xc[n][d] bf16 = invz_h[n] * sum of 4 fp32 partials. 8 elems/thread.
// ---------------------------------------------------------------------------
__global__ __launch_bounds__(256)
void av_red(const float* __restrict__ P, const float* __restrict__ invzb,
            unsigned short* __restrict__ xc)
{
    const long idx = (long)(blockIdx.x * 256 + threadIdx.x) * 8;
    const int n = (int)(idx >> 9);
    const int d0 = (int)(idx & 511);
    const float iz = invzb[(d0 >> 6) * 2048 + n];
    float s[8] = {};
#pragma unroll
    for (int p = 0; p < 4; p++) {
        const float* pp = P + (long)p * 1048576 + idx;
        float4 a = *reinterpret_cast<const float4*>(pp);
        float4 b = *reinterpret_cast<const float4*>(pp + 4);
        s[0] += a.x; s[1] += a.y; s[2] += a.z; s[3] += a.w;
        s[4] += b.x; s[5] += b.y; s[6] += b.z; s[7] += b.w;
    }
    EU o;
#pragma unroll
    for (int j = 0; j < 8; j++) o.u[j] = f2bf(s[j] * iz);
    *reinterpret_cast<bf16x8*>(xc + idx) = o.v;
}

// ---------------------------------------------------------------------------
// out = xc @ Wo.T + bo via bf16 MFMA, fp32 out. grid (32 n-tiles, 8 d-tiles).
// ---------------------------------------------------------------------------
__global__ __launch_bounds__(256)
void out_mfma(const unsigned short* __restrict__ xc,
              const unsigned short* __restrict__ sW,   // seg 3 = Wo
              const float* __restrict__ bo,
              float* __restrict__ out)
{
    const int bx = blockIdx.x;
    const int by = blockIdx.y;
    const int wv = threadIdx.x >> 6;
    const int lane = threadIdx.x & 63;
    const int row  = lane & 15;
    const int koct = (lane >> 4) * 8;
    const int n0 = bx * 64;

    const unsigned short* Ap = xc + (long)(n0 + wv * 16 + row) * 512;
    const unsigned short* Bp = sW + 3L * 262144 + (long)(by * 64 + row) * 512;

    f32x4 acc[4] = {};
#pragma unroll
    for (int k0 = 0; k0 < 512; k0 += 32) {
        bf16x8 a = *reinterpret_cast<const bf16x8*>(Ap + k0 + koct);
#pragma unroll
        for (int t = 0; t < 4; t++) {
            bf16x8 b = *reinterpret_cast<const bf16x8*>(Bp + (long)(t * 16) * 512 + k0 + koct);
            acc[t] = __builtin_amdgcn_mfma_f32_16x16x32_bf16(a, b, acc[t], 0, 0, 0);
        }
    }

    const int rbase = n0 + wv * 16 + (lane >> 4) * 4;
    const int dcol = lane & 15;
#pragma unroll
    for (int t = 0; t < 4; t++) {
        const int col = by * 64 + t * 16 + dcol;
        const float bb = bo[col];
#pragma unroll
        for (int r = 0; r < 4; r++)
            out[(long)(rbase + r) * 512 + col] = acc[t][r] + bb;
    }
}

// ---------------------------------------------------------------------------
extern "C" void kernel_launch(void* const* d_in, const int* in_sizes, int n_in,
                              void* d_out, int out_size, void* d_ws, size_t ws_size,
                              hipStream_t stream)
{
    (void)in_sizes; (void)n_in; (void)out_size; (void)ws_size;

    const float* xyz   = (const float*)d_in[0];
    const float* strf  = (const float*)d_in[1];
    // d_in[2] esm_feat: dead code (DCE'd in reference)
    const float* yhat  = (const float*)d_in[3];
    const int*   dmask = (const int*)d_in[4];
    const float* tptr  = (const float*)d_in[5];
    const float* bwptr = (const float*)d_in[6];
    // d_in[7] max_iter = 5 (fixed)
    const float* Wq = (const float*)d_in[8];
    const float* bq = (const float*)d_in[9];
    const float* Wk = (const float*)d_in[10];
    const float* bk = (const float*)d_in[11];
    const float* Wv = (const float*)d_in[12];
    const float* bv = (const float*)d_in[13];
    const float* Wo = (const float*)d_in[14];
    const float* bo = (const float*)d_in[15];
    float* outp = (float*)d_out;

    char* wsb = (char*)d_ws;
    float* Ppart         = (float*)(wsb);                        // [4][2048][512] f32, 16 MB
    unsigned short* xc   = (unsigned short*)(wsb + (16L << 20)); // 2 MB
    unsigned short* sA   = (unsigned short*)(wsb + (18L << 20)); // 2 MB
    unsigned short* sW   = (unsigned short*)(wsb + (20L << 20)); // [4][262144] bf16, 2 MB
    unsigned short* qh   = (unsigned short*)(wsb + (22L << 20)); // 2 MB
    unsigned short* kh   = (unsigned short*)(wsb + (24L << 20)); // 2 MB
    unsigned short* vT   = (unsigned short*)(wsb + (26L << 20)); // 2 MB
    float* xyzA          = (float*)(wsb + (28L << 20));
    float* xyzB          = xyzA + 8192;
    unsigned char* mby   = (unsigned char*)(wsb + (30L << 20));  // 4 MB
    unsigned short* Ebf  = (unsigned short*)(wsb + (34L << 20)); // [8][2048][2048] bf16, 64 MB
    unsigned short* gbf  = (unsigned short*)(wsb + (98L << 20)); // [2048][2048] bf16, 8 MB
    float* invzb         = (float*)(wsb + (106L << 20));         // [8][2048] f32, 64 KB

    dim3 blk(256, 1, 1);

    // bf16 conversions (incl. Wo) + byte mask + q/k/v MFMA projections
    conv_all<<<dim3(3072), blk, 0, stream>>>(strf, Wq, Wk, Wv, Wo, dmask, sA, sW, mby);
    qkv_mfma<<<dim3(32, 8, 3), blk, 0, stream>>>(sA, sW, bq, bk, bv, qh, kh, vT);

    // E = mask ? exp(q·k/(8t)) : 0, bf16, [h][n][m], coalesced row stores
    scores_rows<<<dim3(128, 8), blk, 0, stream>>>(qh, kh, mby, tptr, Ebf);

    // 5 mean-shift iterations (async LDS staging); last stores g + invz
    const float* src = xyz;
    float* dsts[5] = {xyzA, xyzB, xyzA, xyzB, outp};
    for (int it = 0; it < 5; it++) {
        ms_iter<<<dim3(2048), blk, 0, stream>>>(Ebf, src, dsts[it], yhat, bwptr,
                                                gbf, invzb, it == 4 ? 1 : 0);
        src = dsts[it];
    }

    // x = (E⊙g) @ v (LDS-staged fused A), split-K partials, reduce*invz, out-proj
    av_mfma<<<dim3(32, 4, 8), blk, 0, stream>>>(Ebf, gbf, vT, Ppart);
    av_red<<<dim3(512), blk, 0, stream>>>(Ppart, invzb, xc);
    out_mfma<<<dim3(32, 8), blk, 0, stream>>>(xc, sW, bo, outp + 6144);
}